// Round 3
// baseline (115.804 us; speedup 1.0000x reference)
//
#include <hip/hip_runtime.h>
#include <stdint.h>

#define B_ 64
#define S_ 512
#define EMB_ 256
#define NIN_ 7
#define NOUT_ 4
#define HID_ 512
#define VOCAB_ 1000
#define VP_ 1024          // vocab padded to 1024 rows
#define NG_ 2048          // table cols: [fwd z/f interleaved 1024 | bwd 1024]

typedef __bf16 bf16x8 __attribute__((ext_vector_type(8)));
typedef float floatx4 __attribute__((ext_vector_type(4)));
typedef unsigned short u16x8 __attribute__((ext_vector_type(8)));
typedef unsigned long long ull;

__device__ __forceinline__ unsigned short f2bf(float f) {
    unsigned u = __float_as_uint(f);
    u += 0x7FFFu + ((u >> 16) & 1u);   // RNE
    return (unsigned short)(u >> 16);
}
__device__ __forceinline__ float bf2f(unsigned short h) {
    return __uint_as_float(((unsigned)h) << 16);
}
__device__ __forceinline__ float rcp_(float x) { return __builtin_amdgcn_rcpf(x); }
__device__ __forceinline__ float exp2_(float x) {
    float r; asm("v_exp_f32 %0, %1" : "=v"(r) : "v"(x)); return r;
}
#define L2E_ 1.4426950408889634f
__device__ __forceinline__ float sigmoidf_(float x) {
    return rcp_(1.0f + exp2_(x * (-L2E_)));
}
__device__ __forceinline__ float tanhf_(float x) {
    float ax = fabsf(x);
    float e = exp2_(ax * (-2.0f * L2E_));
    float t = (1.0f - e) * rcp_(1.0f + e);
    return copysignf(t, x);
}

// R3: same persistent mega-kernel as R2, but the barrier cost model is fixed.
// R2 post-mortem: VALUBusy 8.7% over 167us => ~90% idle. Cause: ACQUIRE
// atomic inside the poll loop => one full L2 invalidate PER POLL ITERATION
// (thousands), plus RELEASE wbl2 per arrival. Fix:
//   - spin on RELAXED agent atomic (plain coherent-point read, no cache ops)
//   - ONE fence(acquire,"agent") after spin exit; ONE fence(release,"agent")
//     before arrive. 212 wbl2 + 640 inv total, vs ~1e5 in R2.
//   - barrier #3 eliminated: PQ written via 8B relaxed agent atomic stores
//     (global_store_dwordx2 sc1, write-through to coherent point, no wbl2);
//     per-batch counter; 8th-arriving chunk-block runs the final fold inline
//     (8B atomic PQ loads). Fuses K4, removes the 512-block grid tail.
// Fallback if not co-resident: 3 phase-sliced launches (kernel boundaries
// provide coherence; per-batch final trigger is intra-dispatch and safe).

__device__ __forceinline__ void arrive_(unsigned* c) {
    __syncthreads();                        // drains stores (vmcnt0)
    if (threadIdx.x == 0) {
        __builtin_amdgcn_fence(__ATOMIC_RELEASE, "agent");   // one wbl2
        __hip_atomic_fetch_add(c, 1u, __ATOMIC_RELAXED, __HIP_MEMORY_SCOPE_AGENT);
    }
}
__device__ __forceinline__ void await_(unsigned* c, unsigned target) {
    if (threadIdx.x == 0) {
        while (__hip_atomic_load(c, __ATOMIC_RELAXED, __HIP_MEMORY_SCOPE_AGENT) < target)
            __builtin_amdgcn_s_sleep(8);
        __builtin_amdgcn_fence(__ATOMIC_ACQUIRE, "agent");   // one inv
    }
    __syncthreads();
}

union ShU {
    float raw[32][132];                     // WT transpose staging (16.9 KB)
    struct { float LX[512]; float LN[64][4]; } s;   // scan
    float red[8];                           // final
};

__global__ __launch_bounds__(512, 4) void mega(
    const float* __restrict__ X, const float* __restrict__ emb,
    const float* __restrict__ Wn, const float* __restrict__ bn,
    const float* __restrict__ Wf, const float* __restrict__ bfv,
    const float* __restrict__ Wb, const float* __restrict__ bb,
    const float* __restrict__ Wo, const float* __restrict__ bo,
    unsigned short* __restrict__ Aemb, unsigned short* __restrict__ WT,
    unsigned short* __restrict__ G, float* __restrict__ W4,
    float* __restrict__ bvec, float* __restrict__ PQ,
    unsigned* __restrict__ bar, float* __restrict__ out, int phase) {
    __shared__ ShU U;
    __shared__ unsigned lastf;
    const int bid = blockIdx.x;
    const int tid = threadIdx.x;
    const bool multi = (phase == 0);
    unsigned* bcnt = bar + 2;               // 64 per-batch counters

    // ================= phase P: prep (blocks 0..83) =========================
    if (multi || phase == 1) {
        if (bid < 64) {                     // ---- Aemb: rows 16*bid..+15
            int g = bid;
            int t = tid;
            int r15 = t & 15;
            int kchunk = (t >> 4) & 3;
            int kt = t >> 6;                // 0..7
            int row = g * 16 + r15;
            int k0 = kt * 32 + kchunk * 8;
            unsigned short p[8];
            if (row < VOCAB_) {
                float4 a = *(const float4*)(emb + (size_t)row * EMB_ + k0);
                float4 b = *(const float4*)(emb + (size_t)row * EMB_ + k0 + 4);
                p[0]=f2bf(a.x); p[1]=f2bf(a.y); p[2]=f2bf(a.z); p[3]=f2bf(a.w);
                p[4]=f2bf(b.x); p[5]=f2bf(b.y); p[6]=f2bf(b.z); p[7]=f2bf(b.w);
            } else {
#pragma unroll
                for (int q = 0; q < 8; ++q) p[q] = 0;
            }
            size_t chunk = ((size_t)(g >> 3) * 8 + kt) * 8 + (g & 7);
            *(u16x8*)(Aemb + chunk * 512 + (16 * kchunk + r15) * 8) =
                *(const u16x8*)p;
        } else if (bid < 80) {              // ---- WT: coalesced read + LDS transpose
            int idx = bid - 64;             // 0..15
            int p = idx >> 3;               // part: 0 fwd, 1 bwd
            int gq = idx & 7;               // col-stripe: j0 = gq*64
            const float* W = p ? Wb : Wf;
            int j0 = gq * 64;
            int r = tid >> 3;
            int i = tid & 7;

#pragma unroll
            for (int kt = 0; kt < 8; ++kt) {
                int k0 = kt * 32;
                if (tid < 256) {
                    const float* src = W + (size_t)(k0 + r) * 1536;
                    float4 a0 = *(const float4*)(src + j0 + i * 8);
                    float4 a1 = *(const float4*)(src + j0 + i * 8 + 4);
                    float4 b0 = *(const float4*)(src + 512 + j0 + i * 8);
                    float4 b1 = *(const float4*)(src + 512 + j0 + i * 8 + 4);
                    *(float4*)&U.raw[r][i * 8]          = a0;
                    *(float4*)&U.raw[r][i * 8 + 4]      = a1;
                    *(float4*)&U.raw[r][64 + i * 8]     = b0;
                    *(float4*)&U.raw[r][64 + i * 8 + 4] = b1;
                }
                __syncthreads();
                {
                    int e = tid;            // 0..511 fragment entries
                    int gl = e >> 6;
                    int rest = e & 63;
                    int kchunk = rest >> 4;
                    int v15 = rest & 15;
                    int joff = gl * 8 + (v15 >> 1);
                    int cl = joff + 64 * (v15 & 1);
                    unsigned short pk[8];
#pragma unroll
                    for (int q = 0; q < 8; ++q) pk[q] = f2bf(U.raw[kchunk * 8 + q][cl]);
                    int g = p * 64 + gq * 8 + gl;
                    size_t chunk = ((size_t)(g >> 3) * 8 + kt) * 8 + (g & 7);
                    *(u16x8*)(WT + chunk * 512 + (16 * kchunk + v15) * 8) =
                        *(const u16x8*)pk;
                }
                __syncthreads();
            }
        } else if (bid < 84) {              // ---- W4 (4 x 2048) + bvec (2048)
            int v = (bid - 80) * 512 + tid;
            int part = v >> 10;
            int m = v & 1023;
            int j = m >> 1;
            int c = (m & 1) ? (512 + j) : j;
            const float* W = part ? Wb : Wf;
            float bv = part ? bb[c] : bfv[c];
#pragma unroll
            for (int q = 0; q < NOUT_; ++q) {
                float w = W[(size_t)(256 + q) * 1536 + c];
                W4[(size_t)q * NG_ + v] = w;
                bv = fmaf(bn[q], w, bv);
            }
            bvec[v] = bv;
        }
    }
    if (multi && bid < 84) arrive_(bar + 0);

    // ================= phase G: gemm (blocks 0..127, 8 waves) ===============
    if ((multi || phase == 2) && bid < 128) {
        if (multi) await_(bar + 0, 84u);
        int mtile = bid & 7;
        int ntile = bid >> 3;               // 0..15
        int r0 = mtile * 128;
        int n0 = ntile * 128;
        int lane = tid & 63, wave = tid >> 6;
        int wm = wave & 1;
        int wn = wave >> 1;                 // 0..3: cols 32*wn
        int rl = lane & 15;

        const unsigned short* pa = Aemb + ((size_t)mtile * 64 + 4 * wm) * 512 + lane * 8;
        const unsigned short* pb = WT + ((size_t)ntile * 64 + 2 * wn) * 512 + lane * 8;

        floatx4 acc[4][2];
#pragma unroll
        for (int mi = 0; mi < 4; ++mi)
#pragma unroll
            for (int ni = 0; ni < 2; ++ni) acc[mi][ni] = (floatx4){0.f, 0.f, 0.f, 0.f};

        bf16x8 afc[4], bfc[2], afn[4], bfn[2];
#pragma unroll
        for (int mi = 0; mi < 4; ++mi) afc[mi] = *(const bf16x8*)(pa + mi * 512);
#pragma unroll
        for (int ni = 0; ni < 2; ++ni) bfc[ni] = *(const bf16x8*)(pb + ni * 512);

#pragma unroll
        for (int kt = 0; kt < 8; ++kt) {
            if (kt < 7) {
#pragma unroll
                for (int mi = 0; mi < 4; ++mi)
                    afn[mi] = *(const bf16x8*)(pa + (size_t)(kt + 1) * 4096 + mi * 512);
#pragma unroll
                for (int ni = 0; ni < 2; ++ni)
                    bfn[ni] = *(const bf16x8*)(pb + (size_t)(kt + 1) * 4096 + ni * 512);
            }
#pragma unroll
            for (int mi = 0; mi < 4; ++mi)
#pragma unroll
                for (int ni = 0; ni < 2; ++ni)
                    acc[mi][ni] = __builtin_amdgcn_mfma_f32_16x16x32_bf16(afc[mi], bfc[ni], acc[mi][ni], 0, 0, 0);
            if (kt < 7) {
#pragma unroll
                for (int mi = 0; mi < 4; ++mi) afc[mi] = afn[mi];
#pragma unroll
                for (int ni = 0; ni < 2; ++ni) bfc[ni] = bfn[ni];
            }
        }

        // C/D: col = lane&15, row = (lane>>4)*4 + reg  [m89/m91]
#pragma unroll
        for (int ni = 0; ni < 2; ++ni) {
            int n = n0 + 32 * wn + 16 * ni + rl;
            float bv = bvec[n];
#pragma unroll
            for (int mi = 0; mi < 4; ++mi) {
                int rb = r0 + 64 * wm + 16 * mi + (lane >> 4) * 4;
#pragma unroll
                for (int v = 0; v < 4; ++v)
                    G[(size_t)(rb + v) * NG_ + n] = f2bf(acc[mi][ni][v] + bv);
            }
        }
    }
    if (multi && bid < 128) arrive_(bar + 1);

    // ================= phase S: scan (all 512 blocks) + inline final ========
    if (multi || phase == 3) {
        int b = bid >> 3, chunk = bid & 7;
        int s0 = chunk * 64;
        int j = tid;

        // pre-await work (X is an input; no dependency on earlier phases)
        U.s.LX[j] = X[((size_t)b * S_ + s0 + (j >> 3)) * 8 + (j & 7)];
        __syncthreads();
        if (j < 256) {                      // token t = j>>2, output q = j&3
            int t = j >> 2, q = j & 3;
            float s = 0.f;
#pragma unroll
            for (int i = 0; i < NIN_; ++i)
                s = fmaf(U.s.LX[t * 8 + 1 + i], Wn[i * NOUT_ + q], s);
            U.s.LN[t][q] = s;
        }
        __syncthreads();                    // LN ready (also covers !multi path)

        if (multi) await_(bar + 1, 128u);

        float2 w4p[NOUT_];
#pragma unroll
        for (int q = 0; q < NOUT_; ++q)
            w4p[q] = *(const float2*)(W4 + (size_t)q * NG_ + 2 * j);

        float P = 1.f, Q = 0.f;
        int ev0 = (int)U.s.LX[0];
        unsigned gpA = *(const unsigned*)(G + (size_t)ev0 * NG_ + 2 * j);
        int ev1 = (int)U.s.LX[8];
        unsigned gpB = *(const unsigned*)(G + (size_t)ev1 * NG_ + 2 * j);
#pragma unroll 4
        for (int s = 0; s < 64; ++s) {
            unsigned gpc = gpA;
            gpA = gpB;
            if (s < 62) {                   // 2-deep prefetch
                int evn = (int)U.s.LX[(s + 2) * 8];
                gpB = *(const unsigned*)(G + (size_t)evn * NG_ + 2 * j);
            }
            float gz = bf2f((unsigned short)(gpc & 0xffffu));
            float gf = bf2f((unsigned short)(gpc >> 16));
            float4 n4 = *(const float4*)(&U.s.LN[s][0]);
            gz = fmaf(n4.x, w4p[0].x, gz);
            gz = fmaf(n4.y, w4p[1].x, gz);
            gz = fmaf(n4.z, w4p[2].x, gz);
            gz = fmaf(n4.w, w4p[3].x, gz);
            gf = fmaf(n4.x, w4p[0].y, gf);
            gf = fmaf(n4.y, w4p[1].y, gf);
            gf = fmaf(n4.z, w4p[2].y, gf);
            gf = fmaf(n4.w, w4p[3].y, gf);
            float z = tanhf_(gz);
            float f = sigmoidf_(gf);
            Q = fmaf(f, Q - z, z);          // f*Q + (1-f)*z
            P *= f;
        }
        {   // write-through 8B store to the coherent point (no wbl2 needed)
            union { float2 f; ull q; } pv;
            pv.f = make_float2(P, Q);
            __hip_atomic_store((ull*)PQ + (size_t)bid * 512 + j, pv.q,
                               __ATOMIC_RELAXED, __HIP_MEMORY_SCOPE_AGENT);
        }

        // -------- per-batch trigger: 8th-arriving chunk-block runs final ----
        __syncthreads();                    // drains the PQ stores (vmcnt0)
        if (tid == 0) {
            unsigned old = __hip_atomic_fetch_add(bcnt + b, 1u, __ATOMIC_RELAXED,
                                                  __HIP_MEMORY_SCOPE_AGENT);
            lastf = (old == 7u);
        }
        __syncthreads();

        if (lastf) {                        // ---- final fold for batch b ----
            float h = 0.f;
#pragma unroll
            for (int c = 0; c < 8; ++c) {
                union { float2 f; ull q; } pv;
                pv.q = __hip_atomic_load((const ull*)PQ + ((size_t)b * 8 + c) * 512 + j,
                                         __ATOMIC_RELAXED, __HIP_MEMORY_SCOPE_AGENT);
                h = fmaf(pv.f.x, h, pv.f.y);
            }

            const float* xr = X + ((size_t)b * S_ + (S_ - 1)) * 8;
            int ev = (int)xr[0];
            float n4[NOUT_];
#pragma unroll
            for (int q = 0; q < NOUT_; ++q) {
                float s = 0.f;
#pragma unroll
                for (int i = 0; i < NIN_; ++i) s = fmaf(xr[1 + i], Wn[i * NOUT_ + q], s);
                n4[q] = s;
            }
            unsigned gpc = *(const unsigned*)(G + (size_t)ev * NG_ + 1024 + 2 * j);
            float gz = bf2f((unsigned short)(gpc & 0xffffu));
            float gf = bf2f((unsigned short)(gpc >> 16));
#pragma unroll
            for (int q = 0; q < NOUT_; ++q) {
                float2 w = *(const float2*)(W4 + (size_t)q * NG_ + 1024 + 2 * j);
                gz = fmaf(n4[q], w.x, gz);
                gf = fmaf(n4[q], w.y, gf);
            }
            float hb = (1.f - sigmoidf_(gf)) * tanhf_(gz);

            float partial = fmaf(h, Wo[j], hb * Wo[512 + j]);
#pragma unroll
            for (int off = 32; off > 0; off >>= 1)
                partial += __shfl_down(partial, off);
            if ((j & 63) == 0) U.red[j >> 6] = partial;
            __syncthreads();
            if (j == 0) {
                float s = bo[0];
#pragma unroll
                for (int w = 0; w < 8; ++w) s += U.red[w];
                out[b] = s;
            }
        }
    }
}

extern "C" void kernel_launch(void* const* d_in, const int* in_sizes, int n_in,
                              void* d_out, int out_size, void* d_ws, size_t ws_size,
                              hipStream_t stream) {
    const float* X   = (const float*)d_in[0];
    const float* emb = (const float*)d_in[1];
    const float* Wn  = (const float*)d_in[2];
    const float* bn  = (const float*)d_in[3];
    const float* Wf  = (const float*)d_in[4];
    const float* bfv = (const float*)d_in[5];
    const float* Wb  = (const float*)d_in[6];
    const float* bb  = (const float*)d_in[7];
    const float* Wo  = (const float*)d_in[8];
    const float* bo  = (const float*)d_in[9];
    float* out = (float*)d_out;

    size_t off_A   = 0;
    size_t off_WT  = off_A  + (size_t)VP_ * EMB_ * 2;          // 512 KB
    size_t off_G   = off_WT + (size_t)NG_ * EMB_ * 2;          // +1 MB
    size_t off_W4  = off_G  + (size_t)VP_ * NG_ * 2;           // +4 MB
    size_t off_bv  = off_W4 + (size_t)NOUT_ * NG_ * 4;         // +32 KB
    size_t off_PQ  = off_bv + (size_t)NG_ * 4;                 // +8 KB
    size_t off_bar = off_PQ + (size_t)B_ * 8 * 512 * 2 * sizeof(float);  // +2 MB
    size_t need    = off_bar + (2 + 64) * sizeof(unsigned);
    if (ws_size < need) return;

    unsigned short* Aemb = (unsigned short*)((char*)d_ws + off_A);
    unsigned short* WT   = (unsigned short*)((char*)d_ws + off_WT);
    unsigned short* G    = (unsigned short*)((char*)d_ws + off_G);
    float*          W4   = (float*)((char*)d_ws + off_W4);
    float*          bvec = (float*)((char*)d_ws + off_bv);
    float*          PQ   = (float*)((char*)d_ws + off_PQ);
    unsigned*       bar  = (unsigned*)((char*)d_ws + off_bar);

    // Co-residency check (host-only, capture-safe); cached across calls.
    static int coop = -1;
    if (coop < 0) {
        int nb = 0;
        hipError_t e = hipOccupancyMaxActiveBlocksPerMultiprocessor(&nb, mega, 512, 0);
        coop = (e == hipSuccess && nb >= 2) ? 1 : 0;
    }

    hipMemsetAsync((char*)d_ws + off_bar, 0, (2 + 64) * sizeof(unsigned), stream);
    if (coop) {
        mega<<<512, 512, 0, stream>>>(X, emb, Wn, bn, Wf, bfv, Wb, bb, Wo, bo,
                                      Aemb, WT, G, W4, bvec, PQ, bar, out, 0);
    } else {
        for (int p = 1; p <= 3; ++p)
            mega<<<512, 512, 0, stream>>>(X, emb, Wn, bn, Wf, bfv, Wb, bb, Wo, bo,
                                          Aemb, WT, G, W4, bvec, PQ, bar, out, p);
    }
}

// Round 4
// 110.851 us; speedup vs baseline: 1.0447x; 1.0447x over previous
//
#include <hip/hip_runtime.h>
#include <stdint.h>

#define B_ 64
#define S_ 512
#define EMB_ 256
#define NIN_ 7
#define NOUT_ 4
#define HID_ 512
#define VOCAB_ 1000
#define VP_ 1024          // vocab padded to 1024 rows
#define NG_ 2048          // table cols: [fwd z/f interleaved 1024 | bwd 1024]

typedef __bf16 bf16x8 __attribute__((ext_vector_type(8)));
typedef float floatx4 __attribute__((ext_vector_type(4)));
typedef unsigned short u16x8 __attribute__((ext_vector_type(8)));

__device__ __forceinline__ unsigned short f2bf(float f) {
    unsigned u = __float_as_uint(f);
    u += 0x7FFFu + ((u >> 16) & 1u);   // RNE
    return (unsigned short)(u >> 16);
}
__device__ __forceinline__ float bf2f(unsigned short h) {
    return __uint_as_float(((unsigned)h) << 16);
}
__device__ __forceinline__ float rcp_(float x) { return __builtin_amdgcn_rcpf(x); }
__device__ __forceinline__ float exp2_(float x) {
    float r; asm("v_exp_f32 %0, %1" : "=v"(r) : "v"(x)); return r;
}
#define L2E_ 1.4426950408889634f
__device__ __forceinline__ float sigmoidf_(float x) {
    return rcp_(1.0f + exp2_(x * (-L2E_)));
}
__device__ __forceinline__ float tanhf_(float x) {
    float ax = fabsf(x);
    float e = exp2_(ax * (-2.0f * L2E_));
    float t = (1.0f - e) * rcp_(1.0f + e);
    return copysignf(t, x);
}

// R4 structure notes (session ledger):
//  - R2/R3 proved single-dispatch persistent barriers are NOT worth it here:
//    launch gaps in the captured graph are tiny (single dispatch timed WORSE,
//    115.8 vs 109.9), and the resident-grid spin has a 30ms tail under any
//    co-tenant perturbation. Multi-dispatch is deterministic. Do not go back.
//  - R3 profile (58us, VALUBusy 25%) => ~75% of in-kernel time is stall; the
//    scan's G gathers are L3 hits (~400-500cyc) after the G-producing phase's
//    L2 writeback; 2-deep prefetch could not cover it.
//  - R4: depth-8 G prefetch ring + LDS row-offset table in scan; WT prep
//    parallelized to 128 one-shot jobs (was 16 blocks x 8 serial k-tiles).

// ---------------- K1: prep: Aemb frags, WT frags, W4/bvec -------------------
// grid 200 x 256: [0,64) Aemb | [64,192) WT jobs (stripe,kt) | [192,200) W4
__global__ __launch_bounds__(256) void prep(
    const float* __restrict__ emb, const float* __restrict__ bn,
    const float* __restrict__ Wf, const float* __restrict__ bfv,
    const float* __restrict__ Wb, const float* __restrict__ bb,
    unsigned short* __restrict__ Aemb, unsigned short* __restrict__ WT,
    float* __restrict__ W4, float* __restrict__ bvec) {
    int bid = blockIdx.x;
    int tid = threadIdx.x;

    if (bid < 64) {                         // ---- Aemb: rows 16*bid..+15
        int g = bid;
#pragma unroll
        for (int half = 0; half < 2; ++half) {
            int t = tid + 256 * half;
            int r15 = t & 15;
            int kchunk = (t >> 4) & 3;
            int kt = t >> 6;                // 0..7
            int row = g * 16 + r15;
            int k0 = kt * 32 + kchunk * 8;
            unsigned short p[8];
            if (row < VOCAB_) {
                float4 a = *(const float4*)(emb + (size_t)row * EMB_ + k0);
                float4 b = *(const float4*)(emb + (size_t)row * EMB_ + k0 + 4);
                p[0]=f2bf(a.x); p[1]=f2bf(a.y); p[2]=f2bf(a.z); p[3]=f2bf(a.w);
                p[4]=f2bf(b.x); p[5]=f2bf(b.y); p[6]=f2bf(b.z); p[7]=f2bf(b.w);
            } else {
#pragma unroll
                for (int q = 0; q < 8; ++q) p[q] = 0;
            }
            size_t chunk = ((size_t)(g >> 3) * 8 + kt) * 8 + (g & 7);
            *(u16x8*)(Aemb + chunk * 512 + (16 * kchunk + r15) * 8) =
                *(const u16x8*)p;
        }
    } else if (bid < 192) {                 // ---- WT: one (stripe idx, kt) job
        __shared__ float raw[32][132];      // 32 k-rows x 128 cols (pad 132)
        int job = bid - 64;                 // 0..127
        int idx = job >> 3;                 // 0..15
        int kt  = job & 7;                  // 0..7
        int p = idx >> 3;                   // part: 0 fwd, 1 bwd
        int gq = idx & 7;                   // col-stripe: j0 = gq*64
        const float* W = p ? Wb : Wf;
        int j0 = gq * 64;
        int r = tid >> 3;                   // 0..31 (k-row within tile)
        int i = tid & 7;                    // 0..7  (8 threads per row)
        int k0 = kt * 32;

        const float* src = W + (size_t)(k0 + r) * 1536;
        // stripe A: z-gate cols j0..j0+63; stripe B: f-gate cols 512+j0..+63
        float4 a0 = *(const float4*)(src + j0 + i * 8);
        float4 a1 = *(const float4*)(src + j0 + i * 8 + 4);
        float4 b0 = *(const float4*)(src + 512 + j0 + i * 8);
        float4 b1 = *(const float4*)(src + 512 + j0 + i * 8 + 4);
        *(float4*)&raw[r][i * 8]          = a0;
        *(float4*)&raw[r][i * 8 + 4]      = a1;
        *(float4*)&raw[r][64 + i * 8]     = b0;
        *(float4*)&raw[r][64 + i * 8 + 4] = b1;
        __syncthreads();
#pragma unroll
        for (int h = 0; h < 2; ++h) {
            int e = tid + 256 * h;          // 0..511 fragment entries
            int gl = e >> 6;                // 0..7 local group
            int rest = e & 63;
            int kchunk = rest >> 4;
            int v15 = rest & 15;
            int joff = gl * 8 + (v15 >> 1);
            int cl = joff + 64 * (v15 & 1);
            unsigned short pk[8];
#pragma unroll
            for (int q = 0; q < 8; ++q) pk[q] = f2bf(raw[kchunk * 8 + q][cl]);
            int g = p * 64 + gq * 8 + gl;
            size_t chunk = ((size_t)(g >> 3) * 8 + kt) * 8 + (g & 7);
            *(u16x8*)(WT + chunk * 512 + (16 * kchunk + v15) * 8) =
                *(const u16x8*)pk;
        }
    } else {                                // ---- W4 (4 x 2048) + bvec (2048)
        int v = (bid - 192) * 256 + tid;
        int part = v >> 10;
        int m = v & 1023;
        int j = m >> 1;
        int c = (m & 1) ? (512 + j) : j;
        const float* W = part ? Wb : Wf;
        float bv = part ? bb[c] : bfv[c];
#pragma unroll
        for (int q = 0; q < NOUT_; ++q) {
            float w = W[(size_t)(256 + q) * 1536 + c];
            W4[(size_t)q * NG_ + v] = w;
            bv = fmaf(bn[q], w, bv);
        }
        bvec[v] = bv;
    }
}

// ---------------- K2: G = Aemb @ WT + bvec (1024 x 2048, K=256) -------------
// barrier-free register-double-buffered K-loop.
__global__ __launch_bounds__(256) void gemmG(
    const unsigned short* __restrict__ Aemb, const unsigned short* __restrict__ WT,
    const float* __restrict__ bvec, unsigned short* __restrict__ G) {
    int bid = blockIdx.x;                   // 128 = 8 mtiles x 16 ntiles
    int mtile = bid & 7;
    int ntile = bid >> 3;
    int r0 = mtile * 128;
    int n0 = ntile * 128;
    int tid = threadIdx.x;
    int lane = tid & 63, wave = tid >> 6;
    int wm = wave & 1, wn = wave >> 1;
    int rl = lane & 15;

    const unsigned short* pa = Aemb + ((size_t)mtile * 64 + 4 * wm) * 512 + lane * 8;
    const unsigned short* pb = WT + ((size_t)ntile * 64 + 4 * wn) * 512 + lane * 8;

    floatx4 acc[4][4];
#pragma unroll
    for (int mi = 0; mi < 4; ++mi)
#pragma unroll
        for (int ni = 0; ni < 4; ++ni) acc[mi][ni] = (floatx4){0.f, 0.f, 0.f, 0.f};

    bf16x8 afc[4], bfc[4], afn[4], bfn[4];
#pragma unroll
    for (int mi = 0; mi < 4; ++mi) afc[mi] = *(const bf16x8*)(pa + mi * 512);
#pragma unroll
    for (int ni = 0; ni < 4; ++ni) bfc[ni] = *(const bf16x8*)(pb + ni * 512);

#pragma unroll
    for (int kt = 0; kt < 8; ++kt) {
        if (kt < 7) {
#pragma unroll
            for (int mi = 0; mi < 4; ++mi)
                afn[mi] = *(const bf16x8*)(pa + (size_t)(kt + 1) * 4096 + mi * 512);
#pragma unroll
            for (int ni = 0; ni < 4; ++ni)
                bfn[ni] = *(const bf16x8*)(pb + (size_t)(kt + 1) * 4096 + ni * 512);
        }
#pragma unroll
        for (int mi = 0; mi < 4; ++mi)
#pragma unroll
            for (int ni = 0; ni < 4; ++ni)
                acc[mi][ni] = __builtin_amdgcn_mfma_f32_16x16x32_bf16(afc[mi], bfc[ni], acc[mi][ni], 0, 0, 0);
        if (kt < 7) {
#pragma unroll
            for (int mi = 0; mi < 4; ++mi) afc[mi] = afn[mi];
#pragma unroll
            for (int ni = 0; ni < 4; ++ni) bfc[ni] = bfn[ni];
        }
    }

    // C/D: col = lane&15, row = (lane>>4)*4 + reg  [m89/m91]
#pragma unroll
    for (int ni = 0; ni < 4; ++ni) {
        int n = n0 + 64 * wn + 16 * ni + rl;
        float bv = bvec[n];
#pragma unroll
        for (int mi = 0; mi < 4; ++mi) {
            int rb = r0 + 64 * wm + 16 * mi + (lane >> 4) * 4;
#pragma unroll
            for (int v = 0; v < 4; ++v)
                G[(size_t)(rb + v) * NG_ + n] = f2bf(acc[mi][ni][v] + bv);
        }
    }
}

// ---------------- K3: gather-scan: 512 blocks (b x 8 chunks) x 512 thr ------
__global__ __launch_bounds__(512) void scan(
    const float* __restrict__ X, const unsigned short* __restrict__ G,
    const float* __restrict__ W4, const float* __restrict__ Wn,
    float* __restrict__ PQ) {
    __shared__ float LX[512];               // 64 steps x 8 floats
    __shared__ float LN[64][4];             // per-token n4 = num @ Wn
    __shared__ int   LO[64];                // per-token G row byte-offset
    int bid = blockIdx.x;
    int b = bid >> 3, chunk = bid & 7;
    int s0 = chunk * 64;
    int j = threadIdx.x;                    // chain 0..511

    LX[j] = X[((size_t)b * S_ + s0 + (j >> 3)) * 8 + (j & 7)];
    __syncthreads();

    if (j < 64) LO[j] = (int)LX[j * 8] * (NG_ * 2);
    if (j < 256) {                          // token t = j>>2, output q = j&3
        int t = j >> 2, q = j & 3;
        float s = 0.f;
#pragma unroll
        for (int i = 0; i < NIN_; ++i) s = fmaf(LX[t * 8 + 1 + i], Wn[i * NOUT_ + q], s);
        LN[t][q] = s;
    }

    float2 w4p[NOUT_];
#pragma unroll
    for (int q = 0; q < NOUT_; ++q)
        w4p[q] = *(const float2*)(W4 + (size_t)q * NG_ + 2 * j);
    __syncthreads();

    // depth-8 prefetch ring: G gathers are L3 hits (~400-500cyc); 8 steps of
    // compute (~100cyc each) fully cover the latency. Ring index s&7 is static
    // under unroll 8 (keeps gp[] in registers, rule #20).
    const char* Gb = (const char*)G + 4 * j;
    unsigned gp[8];
#pragma unroll
    for (int r = 0; r < 8; ++r)
        gp[r] = *(const unsigned*)(Gb + LO[r]);

    float P = 1.f, Q = 0.f;
#pragma unroll 8
    for (int s = 0; s < 64; ++s) {
        unsigned gpc = gp[s & 7];
        if (s < 56)
            gp[s & 7] = *(const unsigned*)(Gb + LO[s + 8]);
        float gz = bf2f((unsigned short)(gpc & 0xffffu));
        float gf = bf2f((unsigned short)(gpc >> 16));
        float4 n4 = *(const float4*)(&LN[s][0]);    // uniform b128 broadcast
        gz = fmaf(n4.x, w4p[0].x, gz);
        gz = fmaf(n4.y, w4p[1].x, gz);
        gz = fmaf(n4.z, w4p[2].x, gz);
        gz = fmaf(n4.w, w4p[3].x, gz);
        gf = fmaf(n4.x, w4p[0].y, gf);
        gf = fmaf(n4.y, w4p[1].y, gf);
        gf = fmaf(n4.z, w4p[2].y, gf);
        gf = fmaf(n4.w, w4p[3].y, gf);
        float z = tanhf_(gz);
        float f = sigmoidf_(gf);
        Q = fmaf(f, Q - z, z);              // f*Q + (1-f)*z
        P *= f;
    }
    ((float2*)PQ)[(size_t)bid * 512 + j] = make_float2(P, Q);
}

// ---------------- K4: fold chunks + backward (1 step) + Wo dot --------------
__global__ __launch_bounds__(512) void final_out(
    const float* __restrict__ X, const unsigned short* __restrict__ G,
    const float* __restrict__ W4, const float* __restrict__ Wn,
    const float* __restrict__ Wo, const float* __restrict__ bo,
    const float* __restrict__ PQ, float* __restrict__ out) {
    int b = blockIdx.x;
    int j = threadIdx.x;                    // 0..511

    float h = 0.f;
#pragma unroll
    for (int c = 0; c < 8; ++c) {
        float2 pq = ((const float2*)PQ)[((size_t)b * 8 + c) * 512 + j];
        h = fmaf(pq.x, h, pq.y);
    }

    const float* xr = X + ((size_t)b * S_ + (S_ - 1)) * 8;
    int ev = (int)xr[0];
    float n4[NOUT_];
#pragma unroll
    for (int q = 0; q < NOUT_; ++q) {
        float s = 0.f;
#pragma unroll
        for (int i = 0; i < NIN_; ++i) s = fmaf(xr[1 + i], Wn[i * NOUT_ + q], s);
        n4[q] = s;
    }
    unsigned gpc = *(const unsigned*)(G + (size_t)ev * NG_ + 1024 + 2 * j);
    float gz = bf2f((unsigned short)(gpc & 0xffffu));
    float gf = bf2f((unsigned short)(gpc >> 16));
#pragma unroll
    for (int q = 0; q < NOUT_; ++q) {
        float2 w = *(const float2*)(W4 + (size_t)q * NG_ + 1024 + 2 * j);
        gz = fmaf(n4[q], w.x, gz);
        gf = fmaf(n4[q], w.y, gf);
    }
    float hb = (1.f - sigmoidf_(gf)) * tanhf_(gz);

    float partial = fmaf(h, Wo[j], hb * Wo[512 + j]);
#pragma unroll
    for (int off = 32; off > 0; off >>= 1)
        partial += __shfl_down(partial, off);
    __shared__ float red[8];
    if ((j & 63) == 0) red[j >> 6] = partial;
    __syncthreads();
    if (j == 0) {
        float s = bo[0];
#pragma unroll
        for (int w = 0; w < 8; ++w) s += red[w];
        out[b] = s;
    }
}

extern "C" void kernel_launch(void* const* d_in, const int* in_sizes, int n_in,
                              void* d_out, int out_size, void* d_ws, size_t ws_size,
                              hipStream_t stream) {
    const float* X   = (const float*)d_in[0];
    const float* emb = (const float*)d_in[1];
    const float* Wn  = (const float*)d_in[2];
    const float* bn  = (const float*)d_in[3];
    const float* Wf  = (const float*)d_in[4];
    const float* bfv = (const float*)d_in[5];
    const float* Wb  = (const float*)d_in[6];
    const float* bb  = (const float*)d_in[7];
    const float* Wo  = (const float*)d_in[8];
    const float* bo  = (const float*)d_in[9];
    float* out = (float*)d_out;

    size_t off_A  = 0;
    size_t off_WT = off_A  + (size_t)VP_ * EMB_ * 2;          // 512 KB
    size_t off_G  = off_WT + (size_t)NG_ * EMB_ * 2;          // +1 MB
    size_t off_W4 = off_G  + (size_t)VP_ * NG_ * 2;           // +4 MB
    size_t off_bv = off_W4 + (size_t)NOUT_ * NG_ * 4;         // +32 KB
    size_t off_PQ = off_bv + (size_t)NG_ * 4;                 // +8 KB
    size_t need   = off_PQ + (size_t)B_ * 8 * 512 * 2 * sizeof(float);  // +2 MB
    if (ws_size < need) return;

    unsigned short* Aemb = (unsigned short*)((char*)d_ws + off_A);
    unsigned short* WT   = (unsigned short*)((char*)d_ws + off_WT);
    unsigned short* G    = (unsigned short*)((char*)d_ws + off_G);
    float*          W4   = (float*)((char*)d_ws + off_W4);
    float*          bvec = (float*)((char*)d_ws + off_bv);
    float*          PQ   = (float*)((char*)d_ws + off_PQ);

    prep<<<200, 256, 0, stream>>>(emb, bn, Wf, bfv, Wb, bb, Aemb, WT, W4, bvec);
    gemmG<<<128, 256, 0, stream>>>(Aemb, WT, bvec, G);
    scan<<<512, 512, 0, stream>>>(X, G, W4, Wn, PQ);
    final_out<<<64, 512, 0, stream>>>(X, G, W4, Wn, Wo, bo, PQ, out);
}

// Round 5
// 110.661 us; speedup vs baseline: 1.0465x; 1.0017x over previous
//
#include <hip/hip_runtime.h>
#include <stdint.h>

#define B_ 64
#define S_ 512
#define EMB_ 256
#define NIN_ 7
#define NOUT_ 4
#define HID_ 512
#define VOCAB_ 1000
#define VP_ 1024          // vocab padded to 1024 rows
#define NG_ 2048          // W4/bvec virtual cols: [fwd 1024 | bwd 1024]

typedef __bf16 bf16x8 __attribute__((ext_vector_type(8)));
typedef float floatx4 __attribute__((ext_vector_type(4)));
typedef unsigned short u16x8 __attribute__((ext_vector_type(8)));
typedef unsigned long long ull;

__device__ __forceinline__ unsigned short f2bf(float f) {
    unsigned u = __float_as_uint(f);
    u += 0x7FFFu + ((u >> 16) & 1u);   // RNE
    return (unsigned short)(u >> 16);
}
__device__ __forceinline__ float bf2f(unsigned short h) {
    return __uint_as_float(((unsigned)h) << 16);
}
__device__ __forceinline__ float rcp_(float x) { return __builtin_amdgcn_rcpf(x); }
__device__ __forceinline__ float exp2_(float x) {
    float r; asm("v_exp_f32 %0, %1" : "=v"(r) : "v"(x)); return r;
}
#define L2E_ 1.4426950408889634f
__device__ __forceinline__ float sigmoidf_(float x) {
    return rcp_(1.0f + exp2_(x * (-L2E_)));
}
__device__ __forceinline__ float tanhf_(float x) {
    float ax = fabsf(x);
    float e = exp2_(ax * (-2.0f * L2E_));
    float t = (1.0f - e) * rcp_(1.0f + e);
    return copysignf(t, x);
}

// Session ledger (R5):
//  - R1=109.9 / R2=110.6 / R4=110.9 across radically different structures =>
//    ~50us is harness-fixed (256MiB re-poison fill @41us + graph overhead),
//    ~55-60us is pipeline (R3 mega profiled 58us). Micro-opts are sub-noise.
//  - R2/R3: persistent grid barriers are net-negative (fence storms / 30ms
//    spin tails). Multi-dispatch is deterministic. Do not go back.
//  - R5 structural cuts: (a) bwd gates computed only for the 64 last-token
//    rows (Gb, 8 small gemm blocks w/ ev-gathered A frags) instead of the
//    full 1024x1024 bwd half => gemm FLOPs halved, G 4MB->2.1MB, final's
//    bwd read becomes batch-indexed/coalesced; (b) final_out fused into scan
//    via R3-proven per-batch counter (relaxed 8B agent atomics, no spinning);
//    bcnt zeroed by prep. 4 dispatches -> 3.

// ---------------- K1: prep: Aemb frags, WT frags, W4/bvec, bcnt=0 -----------
// grid 200 x 256: [0,64) Aemb | [64,192) WT jobs (stripe,kt) | [192,200) W4
__global__ __launch_bounds__(256) void prep(
    const float* __restrict__ emb, const float* __restrict__ bn,
    const float* __restrict__ Wf, const float* __restrict__ bfv,
    const float* __restrict__ Wb, const float* __restrict__ bb,
    unsigned short* __restrict__ Aemb, unsigned short* __restrict__ WT,
    float* __restrict__ W4, float* __restrict__ bvec,
    unsigned* __restrict__ bcnt) {
    int bid = blockIdx.x;
    int tid = threadIdx.x;

    if (bid < 64) {                         // ---- Aemb: rows 16*bid..+15
        int g = bid;
#pragma unroll
        for (int half = 0; half < 2; ++half) {
            int t = tid + 256 * half;
            int r15 = t & 15;
            int kchunk = (t >> 4) & 3;
            int kt = t >> 6;                // 0..7
            int row = g * 16 + r15;
            int k0 = kt * 32 + kchunk * 8;
            unsigned short p[8];
            if (row < VOCAB_) {
                float4 a = *(const float4*)(emb + (size_t)row * EMB_ + k0);
                float4 b = *(const float4*)(emb + (size_t)row * EMB_ + k0 + 4);
                p[0]=f2bf(a.x); p[1]=f2bf(a.y); p[2]=f2bf(a.z); p[3]=f2bf(a.w);
                p[4]=f2bf(b.x); p[5]=f2bf(b.y); p[6]=f2bf(b.z); p[7]=f2bf(b.w);
            } else {
#pragma unroll
                for (int q = 0; q < 8; ++q) p[q] = 0;
            }
            size_t chunk = ((size_t)(g >> 3) * 8 + kt) * 8 + (g & 7);
            *(u16x8*)(Aemb + chunk * 512 + (16 * kchunk + r15) * 8) =
                *(const u16x8*)p;
        }
    } else if (bid < 192) {                 // ---- WT: one (stripe idx, kt) job
        __shared__ float raw[32][132];      // 32 k-rows x 128 cols (pad 132)
        int job = bid - 64;                 // 0..127
        int idx = job >> 3;                 // 0..15
        int kt  = job & 7;                  // 0..7
        int p = idx >> 3;                   // part: 0 fwd, 1 bwd
        int gq = idx & 7;                   // col-stripe: j0 = gq*64
        const float* W = p ? Wb : Wf;
        int j0 = gq * 64;
        int r = tid >> 3;                   // 0..31 (k-row within tile)
        int i = tid & 7;                    // 0..7  (8 threads per row)
        int k0 = kt * 32;

        const float* src = W + (size_t)(k0 + r) * 1536;
        // stripe A: z-gate cols j0..j0+63; stripe B: f-gate cols 512+j0..+63
        float4 a0 = *(const float4*)(src + j0 + i * 8);
        float4 a1 = *(const float4*)(src + j0 + i * 8 + 4);
        float4 b0 = *(const float4*)(src + 512 + j0 + i * 8);
        float4 b1 = *(const float4*)(src + 512 + j0 + i * 8 + 4);
        *(float4*)&raw[r][i * 8]          = a0;
        *(float4*)&raw[r][i * 8 + 4]      = a1;
        *(float4*)&raw[r][64 + i * 8]     = b0;
        *(float4*)&raw[r][64 + i * 8 + 4] = b1;
        __syncthreads();
#pragma unroll
        for (int h = 0; h < 2; ++h) {
            int e = tid + 256 * h;          // 0..511 fragment entries
            int gl = e >> 6;                // 0..7 local group
            int rest = e & 63;
            int kchunk = rest >> 4;
            int v15 = rest & 15;
            int joff = gl * 8 + (v15 >> 1);
            int cl = joff + 64 * (v15 & 1);
            unsigned short pk[8];
#pragma unroll
            for (int q = 0; q < 8; ++q) pk[q] = f2bf(raw[kchunk * 8 + q][cl]);
            int g = p * 64 + gq * 8 + gl;
            size_t chunk = ((size_t)(g >> 3) * 8 + kt) * 8 + (g & 7);
            *(u16x8*)(WT + chunk * 512 + (16 * kchunk + v15) * 8) =
                *(const u16x8*)pk;
        }
    } else {                                // ---- W4 (4 x 2048) + bvec (2048)
        int v = (bid - 192) * 256 + tid;
        int part = v >> 10;
        int m = v & 1023;
        int j = m >> 1;
        int c = (m & 1) ? (512 + j) : j;
        const float* W = part ? Wb : Wf;
        float bv = part ? bb[c] : bfv[c];
#pragma unroll
        for (int q = 0; q < NOUT_; ++q) {
            float w = W[(size_t)(256 + q) * 1536 + c];
            W4[(size_t)q * NG_ + v] = w;
            bv = fmaf(bn[q], w, bv);
        }
        bvec[v] = bv;
        if (bid == 192 && tid < 64) bcnt[tid] = 0;   // scan's batch counters
    }
}

// ---------------- K2: gemm --------------------------------------------------
// blocks [0,64): fwd G1 = Aemb @ WT_fwd + b   (1024 x 1024, K=256)
// blocks [64,72): bwd Gb = Aemb[ev_last] @ WT_bwd + b   (64 x 1024, K=256)
__global__ __launch_bounds__(256) void gemmG(
    const float* __restrict__ X,
    const unsigned short* __restrict__ Aemb, const unsigned short* __restrict__ WT,
    const float* __restrict__ bvec,
    unsigned short* __restrict__ G1, unsigned short* __restrict__ Gb) {
    int bid = blockIdx.x;
    int tid = threadIdx.x;
    int lane = tid & 63, wave = tid >> 6;
    int rl = lane & 15;

    if (bid < 64) {                         // ================= fwd 128x128 tile
        int mtile = bid & 7;
        int ntile = bid >> 3;               // 0..7 (fwd cols 0..1023)
        int r0 = mtile * 128;
        int n0 = ntile * 128;
        int wm = wave & 1, wn = wave >> 1;

        const unsigned short* pa = Aemb + ((size_t)mtile * 64 + 4 * wm) * 512 + lane * 8;
        const unsigned short* pb = WT + ((size_t)ntile * 64 + 4 * wn) * 512 + lane * 8;

        floatx4 acc[4][4];
#pragma unroll
        for (int mi = 0; mi < 4; ++mi)
#pragma unroll
            for (int ni = 0; ni < 4; ++ni) acc[mi][ni] = (floatx4){0.f, 0.f, 0.f, 0.f};

        bf16x8 afc[4], bfc[4], afn[4], bfn[4];
#pragma unroll
        for (int mi = 0; mi < 4; ++mi) afc[mi] = *(const bf16x8*)(pa + mi * 512);
#pragma unroll
        for (int ni = 0; ni < 4; ++ni) bfc[ni] = *(const bf16x8*)(pb + ni * 512);

#pragma unroll
        for (int kt = 0; kt < 8; ++kt) {
            if (kt < 7) {
#pragma unroll
                for (int mi = 0; mi < 4; ++mi)
                    afn[mi] = *(const bf16x8*)(pa + (size_t)(kt + 1) * 4096 + mi * 512);
#pragma unroll
                for (int ni = 0; ni < 4; ++ni)
                    bfn[ni] = *(const bf16x8*)(pb + (size_t)(kt + 1) * 4096 + ni * 512);
            }
#pragma unroll
            for (int mi = 0; mi < 4; ++mi)
#pragma unroll
                for (int ni = 0; ni < 4; ++ni)
                    acc[mi][ni] = __builtin_amdgcn_mfma_f32_16x16x32_bf16(afc[mi], bfc[ni], acc[mi][ni], 0, 0, 0);
            if (kt < 7) {
#pragma unroll
                for (int mi = 0; mi < 4; ++mi) afc[mi] = afn[mi];
#pragma unroll
                for (int ni = 0; ni < 4; ++ni) bfc[ni] = bfn[ni];
            }
        }

        // C/D: col = lane&15, row = (lane>>4)*4 + reg  [m89/m91]
#pragma unroll
        for (int ni = 0; ni < 4; ++ni) {
            int n = n0 + 64 * wn + 16 * ni + rl;
            float bv = bvec[n];
#pragma unroll
            for (int mi = 0; mi < 4; ++mi) {
                int rb = r0 + 64 * wm + 16 * mi + (lane >> 4) * 4;
#pragma unroll
                for (int v = 0; v < 4; ++v)
                    G1[(size_t)(rb + v) * 1024 + n] = f2bf(acc[mi][ni][v] + bv);
            }
        }
    } else {                                // ================= bwd 64x128 tile
        __shared__ int evs[64];
        int ntile = bid - 64;               // 0..7 (bwd cols 0..1023)
        int n0 = ntile * 128;
        if (tid < 64)
            evs[tid] = (int)X[((size_t)tid * S_ + (S_ - 1)) * 8];
        __syncthreads();

        // per-lane gathered A-frag base: lane l, sub-tile mi reads row
        // R = evs[16*mi + (l&15)] from the Aemb fragment table.
        int cbase[4];
#pragma unroll
        for (int mi = 0; mi < 4; ++mi) {
            int R = evs[16 * mi + rl];
            int g = R >> 4;
            cbase[mi] = (g >> 3) * 32768 + (g & 7) * 512 + (lane >> 4) * 128 + (R & 15) * 8;
        }
        // B: virtual col group gv = 64 + ntile*8 + 2*wave + ni
        const unsigned short* pb = WT + ((size_t)(8 + ntile) * 64 + 2 * wave) * 512 + lane * 8;

        floatx4 acc[4][2];
#pragma unroll
        for (int mi = 0; mi < 4; ++mi)
#pragma unroll
            for (int ni = 0; ni < 2; ++ni) acc[mi][ni] = (floatx4){0.f, 0.f, 0.f, 0.f};

#pragma unroll
        for (int kt = 0; kt < 8; ++kt) {
            bf16x8 afc[4], bfc[2];
#pragma unroll
            for (int mi = 0; mi < 4; ++mi)
                afc[mi] = *(const bf16x8*)(Aemb + (size_t)cbase[mi] + (size_t)kt * 4096);
#pragma unroll
            for (int ni = 0; ni < 2; ++ni)
                bfc[ni] = *(const bf16x8*)(pb + (size_t)kt * 4096 + ni * 512);
#pragma unroll
            for (int mi = 0; mi < 4; ++mi)
#pragma unroll
                for (int ni = 0; ni < 2; ++ni)
                    acc[mi][ni] = __builtin_amdgcn_mfma_f32_16x16x32_bf16(afc[mi], bfc[ni], acc[mi][ni], 0, 0, 0);
        }

#pragma unroll
        for (int ni = 0; ni < 2; ++ni) {
            int n = n0 + 32 * wave + 16 * ni + rl;
            float bv = bvec[1024 + n];
#pragma unroll
            for (int mi = 0; mi < 4; ++mi) {
                int rb = 16 * mi + (lane >> 4) * 4;     // batch row
#pragma unroll
                for (int v = 0; v < 4; ++v)
                    Gb[(size_t)(rb + v) * 1024 + n] = f2bf(acc[mi][ni][v] + bv);
            }
        }
    }
}

// ---------------- K3: gather-scan + fused final fold ------------------------
// 512 blocks (b x 8 chunks) x 512 thr; 8th-arriving chunk block of each batch
// runs the final fold (R3-proven relaxed-atomic handoff, no spinning).
__global__ __launch_bounds__(512) void scanF(
    const float* __restrict__ X, const unsigned short* __restrict__ G1,
    const unsigned short* __restrict__ Gb, const float* __restrict__ W4,
    const float* __restrict__ Wn, const float* __restrict__ Wo,
    const float* __restrict__ bo, float* __restrict__ PQ,
    unsigned* __restrict__ bcnt, float* __restrict__ out) {
    __shared__ float LX[512];               // 64 steps x 8 floats
    __shared__ float LN[64][4];             // per-token n4 = num @ Wn
    __shared__ int   LO[64];                // per-token G1 row byte-offset
    __shared__ unsigned lastf;
    __shared__ float red[8];
    int bid = blockIdx.x;
    int b = bid >> 3, chunk = bid & 7;
    int s0 = chunk * 64;
    int j = threadIdx.x;                    // chain 0..511

    LX[j] = X[((size_t)b * S_ + s0 + (j >> 3)) * 8 + (j & 7)];
    __syncthreads();

    if (j < 64) LO[j] = (int)LX[j * 8] * 2048;   // G1 row = 1024 shorts = 2KB
    if (j < 256) {                          // token t = j>>2, output q = j&3
        int t = j >> 2, q = j & 3;
        float s = 0.f;
#pragma unroll
        for (int i = 0; i < NIN_; ++i) s = fmaf(LX[t * 8 + 1 + i], Wn[i * NOUT_ + q], s);
        LN[t][q] = s;
    }

    float2 w4p[NOUT_];
#pragma unroll
    for (int q = 0; q < NOUT_; ++q)
        w4p[q] = *(const float2*)(W4 + (size_t)q * NG_ + 2 * j);
    __syncthreads();

    // depth-8 prefetch ring (ring index s&7 static under unroll 8, rule #20)
    const char* Gbase = (const char*)G1 + 4 * j;
    unsigned gp[8];
#pragma unroll
    for (int r = 0; r < 8; ++r)
        gp[r] = *(const unsigned*)(Gbase + LO[r]);

    float P = 1.f, Q = 0.f;
#pragma unroll 8
    for (int s = 0; s < 64; ++s) {
        unsigned gpc = gp[s & 7];
        if (s < 56)
            gp[s & 7] = *(const unsigned*)(Gbase + LO[s + 8]);
        float gz = bf2f((unsigned short)(gpc & 0xffffu));
        float gf = bf2f((unsigned short)(gpc >> 16));
        float4 n4 = *(const float4*)(&LN[s][0]);    // uniform b128 broadcast
        gz = fmaf(n4.x, w4p[0].x, gz);
        gz = fmaf(n4.y, w4p[1].x, gz);
        gz = fmaf(n4.z, w4p[2].x, gz);
        gz = fmaf(n4.w, w4p[3].x, gz);
        gf = fmaf(n4.x, w4p[0].y, gf);
        gf = fmaf(n4.y, w4p[1].y, gf);
        gf = fmaf(n4.z, w4p[2].y, gf);
        gf = fmaf(n4.w, w4p[3].y, gf);
        float z = tanhf_(gz);
        float f = sigmoidf_(gf);
        Q = fmaf(f, Q - z, z);              // f*Q + (1-f)*z
        P *= f;
    }
    {   // write-through 8B store to the coherent point (R3-proven)
        union { float2 f; ull q; } pv;
        pv.f = make_float2(P, Q);
        __hip_atomic_store((ull*)PQ + (size_t)bid * 512 + j, pv.q,
                           __ATOMIC_RELAXED, __HIP_MEMORY_SCOPE_AGENT);
    }

    // -------- per-batch trigger: 8th-arriving chunk block runs the fold -----
    __syncthreads();                        // drains the PQ stores (vmcnt0)
    if (j == 0) {
        unsigned old = __hip_atomic_fetch_add(bcnt + b, 1u, __ATOMIC_RELAXED,
                                              __HIP_MEMORY_SCOPE_AGENT);
        lastf = (old == 7u);
    }
    __syncthreads();

    if (lastf) {                            // ---- final fold for batch b ----
        float h = 0.f;
#pragma unroll
        for (int c = 0; c < 8; ++c) {
            union { float2 f; ull q; } pv;
            pv.q = __hip_atomic_load((const ull*)PQ + ((size_t)b * 8 + c) * 512 + j,
                                     __ATOMIC_RELAXED, __HIP_MEMORY_SCOPE_AGENT);
            h = fmaf(pv.f.x, h, pv.f.y);
        }

        const float* xr = X + ((size_t)b * S_ + (S_ - 1)) * 8;
        float n4[NOUT_];
#pragma unroll
        for (int q = 0; q < NOUT_; ++q) {
            float s = 0.f;
#pragma unroll
            for (int i = 0; i < NIN_; ++i) s = fmaf(xr[1 + i], Wn[i * NOUT_ + q], s);
            n4[q] = s;
        }
        unsigned gpc = *(const unsigned*)(Gb + (size_t)b * 1024 + 2 * j);  // coalesced
        float gz = bf2f((unsigned short)(gpc & 0xffffu));
        float gf = bf2f((unsigned short)(gpc >> 16));
#pragma unroll
        for (int q = 0; q < NOUT_; ++q) {
            float2 w = *(const float2*)(W4 + (size_t)q * NG_ + 1024 + 2 * j);
            gz = fmaf(n4[q], w.x, gz);
            gf = fmaf(n4[q], w.y, gf);
        }
        float hb = (1.f - sigmoidf_(gf)) * tanhf_(gz);

        float partial = fmaf(h, Wo[j], hb * Wo[512 + j]);
#pragma unroll
        for (int off = 32; off > 0; off >>= 1)
            partial += __shfl_down(partial, off);
        if ((j & 63) == 0) red[j >> 6] = partial;
        __syncthreads();
        if (j == 0) {
            float s = bo[0];
#pragma unroll
            for (int w = 0; w < 8; ++w) s += red[w];
            out[b] = s;
        }
    }
}

extern "C" void kernel_launch(void* const* d_in, const int* in_sizes, int n_in,
                              void* d_out, int out_size, void* d_ws, size_t ws_size,
                              hipStream_t stream) {
    const float* X   = (const float*)d_in[0];
    const float* emb = (const float*)d_in[1];
    const float* Wn  = (const float*)d_in[2];
    const float* bn  = (const float*)d_in[3];
    const float* Wf  = (const float*)d_in[4];
    const float* bfv = (const float*)d_in[5];
    const float* Wb  = (const float*)d_in[6];
    const float* bb  = (const float*)d_in[7];
    const float* Wo  = (const float*)d_in[8];
    const float* bo  = (const float*)d_in[9];
    float* out = (float*)d_out;

    size_t off_A  = 0;
    size_t off_WT = off_A  + (size_t)VP_ * EMB_ * 2;          // 512 KB
    size_t off_G1 = off_WT + (size_t)NG_ * EMB_ * 2;          // +1 MB
    size_t off_Gb = off_G1 + (size_t)VP_ * 1024 * 2;          // +2 MB
    size_t off_W4 = off_Gb + (size_t)B_ * 1024 * 2;           // +128 KB
    size_t off_bv = off_W4 + (size_t)NOUT_ * NG_ * 4;         // +32 KB
    size_t off_PQ = off_bv + (size_t)NG_ * 4;                 // +8 KB
    size_t off_bc = off_PQ + (size_t)B_ * 8 * 512 * 2 * sizeof(float);  // +2 MB
    size_t need   = off_bc + 64 * sizeof(unsigned);
    if (ws_size < need) return;

    unsigned short* Aemb = (unsigned short*)((char*)d_ws + off_A);
    unsigned short* WT   = (unsigned short*)((char*)d_ws + off_WT);
    unsigned short* G1   = (unsigned short*)((char*)d_ws + off_G1);
    unsigned short* Gb   = (unsigned short*)((char*)d_ws + off_Gb);
    float*          W4   = (float*)((char*)d_ws + off_W4);
    float*          bvec = (float*)((char*)d_ws + off_bv);
    float*          PQ   = (float*)((char*)d_ws + off_PQ);
    unsigned*       bcnt = (unsigned*)((char*)d_ws + off_bc);

    prep<<<200, 256, 0, stream>>>(emb, bn, Wf, bfv, Wb, bb, Aemb, WT, W4, bvec, bcnt);
    gemmG<<<72, 256, 0, stream>>>(X, Aemb, WT, bvec, G1, Gb);
    scanF<<<512, 512, 0, stream>>>(X, G1, Gb, W4, Wn, Wo, bo, PQ, bcnt, out);
}

// Round 6
// 102.431 us; speedup vs baseline: 1.1306x; 1.0803x over previous
//
#include <hip/hip_runtime.h>
#include <stdint.h>

#define B_ 64
#define S_ 512
#define EMB_ 256
#define NIN_ 7
#define NOUT_ 4
#define HID_ 512
#define VOCAB_ 1000
#define VP_ 1024          // vocab padded to 1024 rows
#define NG_ 2048          // W4/bvec virtual cols: [fwd 1024 | bwd 1024]

typedef __bf16 bf16x8 __attribute__((ext_vector_type(8)));
typedef float floatx4 __attribute__((ext_vector_type(4)));
typedef unsigned short u16x8 __attribute__((ext_vector_type(8)));
typedef unsigned long long ull;

__device__ __forceinline__ unsigned short f2bf(float f) {
    unsigned u = __float_as_uint(f);
    u += 0x7FFFu + ((u >> 16) & 1u);   // RNE
    return (unsigned short)(u >> 16);
}
__device__ __forceinline__ float bf2f(unsigned short h) {
    return __uint_as_float(((unsigned)h) << 16);
}
__device__ __forceinline__ float rcp_(float x) { return __builtin_amdgcn_rcpf(x); }
__device__ __forceinline__ float exp2_(float x) {
    float r; asm("v_exp_f32 %0, %1" : "=v"(r) : "v"(x)); return r;
}
#define L2E_ 1.4426950408889634f
__device__ __forceinline__ float sigmoidf_(float x) {
    return rcp_(1.0f + exp2_(x * (-L2E_)));
}
__device__ __forceinline__ float tanhf_(float x) {
    float ax = fabsf(x);
    float e = exp2_(ax * (-2.0f * L2E_));
    float t = (1.0f - e) * rcp_(1.0f + e);
    return copysignf(t, x);
}

// Session ledger (R6):
//  - R1=109.9 R2=110.6 R4=110.9 R5=110.7: dur invariant across 4 structures.
//    => fill ~42us (harness) + pipeline ~52us + slop ~16us. Graph launch gaps
//    are ~free (R5 removed a dispatch: net 0). Persistent grid barriers are
//    net-negative (R2/R3). Micro-opts sub-noise.
//  - R3 clean profile: pipeline 58us @ VALUBusy 25% => ~75% stall; scan is
//    the largest phase. R4's depth-8 ring failed: steady-state chains
//    ds_read(LO) -> global_load -> use, and counted waits re-serialize.
//  - R6: scan gathers fully PRELOADED into registers (64 loads issued in one
//    burst after a batch of LDS address reads; one drain; then fully-unrolled
//    register-only compute). VGPR ~110, capped 128 via launch_bounds(512,4)
//    => still 2 blocks/CU. If this is null, scan is exonerated; next lever is
//    prep->gemm block-local fusion or the floor.

// ---------------- K1: prep: Aemb frags, WT frags, W4/bvec, bcnt=0 -----------
// grid 200 x 256: [0,64) Aemb | [64,192) WT jobs (stripe,kt) | [192,200) W4
__global__ __launch_bounds__(256) void prep(
    const float* __restrict__ emb, const float* __restrict__ bn,
    const float* __restrict__ Wf, const float* __restrict__ bfv,
    const float* __restrict__ Wb, const float* __restrict__ bb,
    unsigned short* __restrict__ Aemb, unsigned short* __restrict__ WT,
    float* __restrict__ W4, float* __restrict__ bvec,
    unsigned* __restrict__ bcnt) {
    int bid = blockIdx.x;
    int tid = threadIdx.x;

    if (bid < 64) {                         // ---- Aemb: rows 16*bid..+15
        int g = bid;
#pragma unroll
        for (int half = 0; half < 2; ++half) {
            int t = tid + 256 * half;
            int r15 = t & 15;
            int kchunk = (t >> 4) & 3;
            int kt = t >> 6;                // 0..7
            int row = g * 16 + r15;
            int k0 = kt * 32 + kchunk * 8;
            unsigned short p[8];
            if (row < VOCAB_) {
                float4 a = *(const float4*)(emb + (size_t)row * EMB_ + k0);
                float4 b = *(const float4*)(emb + (size_t)row * EMB_ + k0 + 4);
                p[0]=f2bf(a.x); p[1]=f2bf(a.y); p[2]=f2bf(a.z); p[3]=f2bf(a.w);
                p[4]=f2bf(b.x); p[5]=f2bf(b.y); p[6]=f2bf(b.z); p[7]=f2bf(b.w);
            } else {
#pragma unroll
                for (int q = 0; q < 8; ++q) p[q] = 0;
            }
            size_t chunk = ((size_t)(g >> 3) * 8 + kt) * 8 + (g & 7);
            *(u16x8*)(Aemb + chunk * 512 + (16 * kchunk + r15) * 8) =
                *(const u16x8*)p;
        }
    } else if (bid < 192) {                 // ---- WT: one (stripe idx, kt) job
        __shared__ float raw[32][132];      // 32 k-rows x 128 cols (pad 132)
        int job = bid - 64;                 // 0..127
        int idx = job >> 3;                 // 0..15
        int kt  = job & 7;                  // 0..7
        int p = idx >> 3;                   // part: 0 fwd, 1 bwd
        int gq = idx & 7;                   // col-stripe: j0 = gq*64
        const float* W = p ? Wb : Wf;
        int j0 = gq * 64;
        int r = tid >> 3;                   // 0..31 (k-row within tile)
        int i = tid & 7;                    // 0..7  (8 threads per row)
        int k0 = kt * 32;

        const float* src = W + (size_t)(k0 + r) * 1536;
        // stripe A: z-gate cols j0..j0+63; stripe B: f-gate cols 512+j0..+63
        float4 a0 = *(const float4*)(src + j0 + i * 8);
        float4 a1 = *(const float4*)(src + j0 + i * 8 + 4);
        float4 b0 = *(const float4*)(src + 512 + j0 + i * 8);
        float4 b1 = *(const float4*)(src + 512 + j0 + i * 8 + 4);
        *(float4*)&raw[r][i * 8]          = a0;
        *(float4*)&raw[r][i * 8 + 4]      = a1;
        *(float4*)&raw[r][64 + i * 8]     = b0;
        *(float4*)&raw[r][64 + i * 8 + 4] = b1;
        __syncthreads();
#pragma unroll
        for (int h = 0; h < 2; ++h) {
            int e = tid + 256 * h;          // 0..511 fragment entries
            int gl = e >> 6;                // 0..7 local group
            int rest = e & 63;
            int kchunk = rest >> 4;
            int v15 = rest & 15;
            int joff = gl * 8 + (v15 >> 1);
            int cl = joff + 64 * (v15 & 1);
            unsigned short pk[8];
#pragma unroll
            for (int q = 0; q < 8; ++q) pk[q] = f2bf(raw[kchunk * 8 + q][cl]);
            int g = p * 64 + gq * 8 + gl;
            size_t chunk = ((size_t)(g >> 3) * 8 + kt) * 8 + (g & 7);
            *(u16x8*)(WT + chunk * 512 + (16 * kchunk + v15) * 8) =
                *(const u16x8*)pk;
        }
    } else {                                // ---- W4 (4 x 2048) + bvec (2048)
        int v = (bid - 192) * 256 + tid;
        int part = v >> 10;
        int m = v & 1023;
        int j = m >> 1;
        int c = (m & 1) ? (512 + j) : j;
        const float* W = part ? Wb : Wf;
        float bv = part ? bb[c] : bfv[c];
#pragma unroll
        for (int q = 0; q < NOUT_; ++q) {
            float w = W[(size_t)(256 + q) * 1536 + c];
            W4[(size_t)q * NG_ + v] = w;
            bv = fmaf(bn[q], w, bv);
        }
        bvec[v] = bv;
        if (bid == 192 && tid < 64) bcnt[tid] = 0;   // scan's batch counters
    }
}

// ---------------- K2: gemm --------------------------------------------------
// blocks [0,64): fwd G1 = Aemb @ WT_fwd + b   (1024 x 1024, K=256)
// blocks [64,72): bwd Gb = Aemb[ev_last] @ WT_bwd + b   (64 x 1024, K=256)
__global__ __launch_bounds__(256) void gemmG(
    const float* __restrict__ X,
    const unsigned short* __restrict__ Aemb, const unsigned short* __restrict__ WT,
    const float* __restrict__ bvec,
    unsigned short* __restrict__ G1, unsigned short* __restrict__ Gb) {
    int bid = blockIdx.x;
    int tid = threadIdx.x;
    int lane = tid & 63, wave = tid >> 6;
    int rl = lane & 15;

    if (bid < 64) {                         // ================= fwd 128x128 tile
        int mtile = bid & 7;
        int ntile = bid >> 3;               // 0..7 (fwd cols 0..1023)
        int r0 = mtile * 128;
        int n0 = ntile * 128;
        int wm = wave & 1, wn = wave >> 1;

        const unsigned short* pa = Aemb + ((size_t)mtile * 64 + 4 * wm) * 512 + lane * 8;
        const unsigned short* pb = WT + ((size_t)ntile * 64 + 4 * wn) * 512 + lane * 8;

        floatx4 acc[4][4];
#pragma unroll
        for (int mi = 0; mi < 4; ++mi)
#pragma unroll
            for (int ni = 0; ni < 4; ++ni) acc[mi][ni] = (floatx4){0.f, 0.f, 0.f, 0.f};

        bf16x8 afc[4], bfc[4], afn[4], bfn[4];
#pragma unroll
        for (int mi = 0; mi < 4; ++mi) afc[mi] = *(const bf16x8*)(pa + mi * 512);
#pragma unroll
        for (int ni = 0; ni < 4; ++ni) bfc[ni] = *(const bf16x8*)(pb + ni * 512);

#pragma unroll
        for (int kt = 0; kt < 8; ++kt) {
            if (kt < 7) {
#pragma unroll
                for (int mi = 0; mi < 4; ++mi)
                    afn[mi] = *(const bf16x8*)(pa + (size_t)(kt + 1) * 4096 + mi * 512);
#pragma unroll
                for (int ni = 0; ni < 4; ++ni)
                    bfn[ni] = *(const bf16x8*)(pb + (size_t)(kt + 1) * 4096 + ni * 512);
            }
#pragma unroll
            for (int mi = 0; mi < 4; ++mi)
#pragma unroll
                for (int ni = 0; ni < 4; ++ni)
                    acc[mi][ni] = __builtin_amdgcn_mfma_f32_16x16x32_bf16(afc[mi], bfc[ni], acc[mi][ni], 0, 0, 0);
            if (kt < 7) {
#pragma unroll
                for (int mi = 0; mi < 4; ++mi) afc[mi] = afn[mi];
#pragma unroll
                for (int ni = 0; ni < 4; ++ni) bfc[ni] = bfn[ni];
            }
        }

        // C/D: col = lane&15, row = (lane>>4)*4 + reg  [m89/m91]
#pragma unroll
        for (int ni = 0; ni < 4; ++ni) {
            int n = n0 + 64 * wn + 16 * ni + rl;
            float bv = bvec[n];
#pragma unroll
            for (int mi = 0; mi < 4; ++mi) {
                int rb = r0 + 64 * wm + 16 * mi + (lane >> 4) * 4;
#pragma unroll
                for (int v = 0; v < 4; ++v)
                    G1[(size_t)(rb + v) * 1024 + n] = f2bf(acc[mi][ni][v] + bv);
            }
        }
    } else {                                // ================= bwd 64x128 tile
        __shared__ int evs[64];
        int ntile = bid - 64;               // 0..7 (bwd cols 0..1023)
        int n0 = ntile * 128;
        if (tid < 64)
            evs[tid] = (int)X[((size_t)tid * S_ + (S_ - 1)) * 8];
        __syncthreads();

        // per-lane gathered A-frag base: lane l, sub-tile mi reads row
        // R = evs[16*mi + (l&15)] from the Aemb fragment table.
        int cbase[4];
#pragma unroll
        for (int mi = 0; mi < 4; ++mi) {
            int R = evs[16 * mi + rl];
            int g = R >> 4;
            cbase[mi] = (g >> 3) * 32768 + (g & 7) * 512 + (lane >> 4) * 128 + (R & 15) * 8;
        }
        // B: virtual col group gv = 64 + ntile*8 + 2*wave + ni
        const unsigned short* pb = WT + ((size_t)(8 + ntile) * 64 + 2 * wave) * 512 + lane * 8;

        floatx4 acc[4][2];
#pragma unroll
        for (int mi = 0; mi < 4; ++mi)
#pragma unroll
            for (int ni = 0; ni < 2; ++ni) acc[mi][ni] = (floatx4){0.f, 0.f, 0.f, 0.f};

#pragma unroll
        for (int kt = 0; kt < 8; ++kt) {
            bf16x8 afc[4], bfc[2];
#pragma unroll
            for (int mi = 0; mi < 4; ++mi)
                afc[mi] = *(const bf16x8*)(Aemb + (size_t)cbase[mi] + (size_t)kt * 4096);
#pragma unroll
            for (int ni = 0; ni < 2; ++ni)
                bfc[ni] = *(const bf16x8*)(pb + (size_t)kt * 4096 + ni * 512);
#pragma unroll
            for (int mi = 0; mi < 4; ++mi)
#pragma unroll
                for (int ni = 0; ni < 2; ++ni)
                    acc[mi][ni] = __builtin_amdgcn_mfma_f32_16x16x32_bf16(afc[mi], bfc[ni], acc[mi][ni], 0, 0, 0);
        }

#pragma unroll
        for (int ni = 0; ni < 2; ++ni) {
            int n = n0 + 32 * wave + 16 * ni + rl;
            float bv = bvec[1024 + n];
#pragma unroll
            for (int mi = 0; mi < 4; ++mi) {
                int rb = 16 * mi + (lane >> 4) * 4;     // batch row
#pragma unroll
                for (int v = 0; v < 4; ++v)
                    Gb[(size_t)(rb + v) * 1024 + n] = f2bf(acc[mi][ni][v] + bv);
            }
        }
    }
}

// ---------------- K3: gather-scan (full register preload) + fused final -----
// 512 blocks (b x 8 chunks) x 512 thr; all 64 G-gathers preloaded into
// registers in one burst, then a fully-unrolled register-only compute loop.
__global__ __launch_bounds__(512, 4) void scanF(
    const float* __restrict__ X, const unsigned short* __restrict__ G1,
    const unsigned short* __restrict__ Gb, const float* __restrict__ W4,
    const float* __restrict__ Wn, const float* __restrict__ Wo,
    const float* __restrict__ bo, float* __restrict__ PQ,
    unsigned* __restrict__ bcnt, float* __restrict__ out) {
    __shared__ float LX[512];               // 64 steps x 8 floats
    __shared__ float LN[64][4];             // per-token n4 = num @ Wn
    __shared__ int   LO[64];                // per-token G1 row byte-offset
    __shared__ unsigned lastf;
    __shared__ float red[8];
    int bid = blockIdx.x;
    int b = bid >> 3, chunk = bid & 7;
    int s0 = chunk * 64;
    int j = threadIdx.x;                    // chain 0..511

    LX[j] = X[((size_t)b * S_ + s0 + (j >> 3)) * 8 + (j & 7)];
    __syncthreads();

    if (j < 64) LO[j] = (int)LX[j * 8] * 2048;   // G1 row = 1024 shorts = 2KB
    if (j < 256) {                          // token t = j>>2, output q = j&3
        int t = j >> 2, q = j & 3;
        float s = 0.f;
#pragma unroll
        for (int i = 0; i < NIN_; ++i) s = fmaf(LX[t * 8 + 1 + i], Wn[i * NOUT_ + q], s);
        LN[t][q] = s;
    }

    float2 w4p[NOUT_];
#pragma unroll
    for (int q = 0; q < NOUT_; ++q)
        w4p[q] = *(const float2*)(W4 + (size_t)q * NG_ + 2 * j);
    __syncthreads();

    // ---- full preload: 64 independent 4B gathers, one burst, one drain ----
    const char* Gbase = (const char*)G1 + 4 * j;
    unsigned gp[64];
#pragma unroll
    for (int m = 0; m < 16; ++m) {
        int4 lo = *(const int4*)&LO[4 * m];
        gp[4 * m + 0] = *(const unsigned*)(Gbase + lo.x);
        gp[4 * m + 1] = *(const unsigned*)(Gbase + lo.y);
        gp[4 * m + 2] = *(const unsigned*)(Gbase + lo.z);
        gp[4 * m + 3] = *(const unsigned*)(Gbase + lo.w);
    }

    float P = 1.f, Q = 0.f;
#pragma unroll
    for (int s = 0; s < 64; ++s) {
        unsigned gpc = gp[s];               // static index (full unroll)
        float gz = bf2f((unsigned short)(gpc & 0xffffu));
        float gf = bf2f((unsigned short)(gpc >> 16));
        float4 n4 = *(const float4*)(&LN[s][0]);    // uniform b128 broadcast
        gz = fmaf(n4.x, w4p[0].x, gz);
        gz = fmaf(n4.y, w4p[1].x, gz);
        gz = fmaf(n4.z, w4p[2].x, gz);
        gz = fmaf(n4.w, w4p[3].x, gz);
        gf = fmaf(n4.x, w4p[0].y, gf);
        gf = fmaf(n4.y, w4p[1].y, gf);
        gf = fmaf(n4.z, w4p[2].y, gf);
        gf = fmaf(n4.w, w4p[3].y, gf);
        float z = tanhf_(gz);
        float f = sigmoidf_(gf);
        Q = fmaf(f, Q - z, z);              // f*Q + (1-f)*z
        P *= f;
    }
    {   // write-through 8B store to the coherent point (R3-proven)
        union { float2 f; ull q; } pv;
        pv.f = make_float2(P, Q);
        __hip_atomic_store((ull*)PQ + (size_t)bid * 512 + j, pv.q,
                           __ATOMIC_RELAXED, __HIP_MEMORY_SCOPE_AGENT);
    }

    // -------- per-batch trigger: 8th-arriving chunk block runs the fold -----
    __syncthreads();                        // drains the PQ stores (vmcnt0)
    if (j == 0) {
        unsigned old = __hip_atomic_fetch_add(bcnt + b, 1u, __ATOMIC_RELAXED,
                                              __HIP_MEMORY_SCOPE_AGENT);
        lastf = (old == 7u);
    }
    __syncthreads();

    if (lastf) {                            // ---- final fold for batch b ----
        float h = 0.f;
#pragma unroll
        for (int c = 0; c < 8; ++c) {
            union { float2 f; ull q; } pv;
            pv.q = __hip_atomic_load((const ull*)PQ + ((size_t)b * 8 + c) * 512 + j,
                                     __ATOMIC_RELAXED, __HIP_MEMORY_SCOPE_AGENT);
            h = fmaf(pv.f.x, h, pv.f.y);
        }

        const float* xr = X + ((size_t)b * S_ + (S_ - 1)) * 8;
        float n4[NOUT_];
#pragma unroll
        for (int q = 0; q < NOUT_; ++q) {
            float s = 0.f;
#pragma unroll
            for (int i = 0; i < NIN_; ++i) s = fmaf(xr[1 + i], Wn[i * NOUT_ + q], s);
            n4[q] = s;
        }
        unsigned gpc = *(const unsigned*)(Gb + (size_t)b * 1024 + 2 * j);  // coalesced
        float gz = bf2f((unsigned short)(gpc & 0xffffu));
        float gf = bf2f((unsigned short)(gpc >> 16));
#pragma unroll
        for (int q = 0; q < NOUT_; ++q) {
            float2 w = *(const float2*)(W4 + (size_t)q * NG_ + 1024 + 2 * j);
            gz = fmaf(n4[q], w.x, gz);
            gf = fmaf(n4[q], w.y, gf);
        }
        float hb = (1.f - sigmoidf_(gf)) * tanhf_(gz);

        float partial = fmaf(h, Wo[j], hb * Wo[512 + j]);
#pragma unroll
        for (int off = 32; off > 0; off >>= 1)
            partial += __shfl_down(partial, off);
        if ((j & 63) == 0) red[j >> 6] = partial;
        __syncthreads();
        if (j == 0) {
            float s = bo[0];
#pragma unroll
            for (int w = 0; w < 8; ++w) s += red[w];
            out[b] = s;
        }
    }
}

extern "C" void kernel_launch(void* const* d_in, const int* in_sizes, int n_in,
                              void* d_out, int out_size, void* d_ws, size_t ws_size,
                              hipStream_t stream) {
    const float* X   = (const float*)d_in[0];
    const float* emb = (const float*)d_in[1];
    const float* Wn  = (const float*)d_in[2];
    const float* bn  = (const float*)d_in[3];
    const float* Wf  = (const float*)d_in[4];
    const float* bfv = (const float*)d_in[5];
    const float* Wb  = (const float*)d_in[6];
    const float* bb  = (const float*)d_in[7];
    const float* Wo  = (const float*)d_in[8];
    const float* bo  = (const float*)d_in[9];
    float* out = (float*)d_out;

    size_t off_A  = 0;
    size_t off_WT = off_A  + (size_t)VP_ * EMB_ * 2;          // 512 KB
    size_t off_G1 = off_WT + (size_t)NG_ * EMB_ * 2;          // +1 MB
    size_t off_Gb = off_G1 + (size_t)VP_ * 1024 * 2;          // +2 MB
    size_t off_W4 = off_Gb + (size_t)B_ * 1024 * 2;           // +128 KB
    size_t off_bv = off_W4 + (size_t)NOUT_ * NG_ * 4;         // +32 KB
    size_t off_PQ = off_bv + (size_t)NG_ * 4;                 // +8 KB
    size_t off_bc = off_PQ + (size_t)B_ * 8 * 512 * 2 * sizeof(float);  // +2 MB
    size_t need   = off_bc + 64 * sizeof(unsigned);
    if (ws_size < need) return;

    unsigned short* Aemb = (unsigned short*)((char*)d_ws + off_A);
    unsigned short* WT   = (unsigned short*)((char*)d_ws + off_WT);
    unsigned short* G1   = (unsigned short*)((char*)d_ws + off_G1);
    unsigned short* Gb   = (unsigned short*)((char*)d_ws + off_Gb);
    float*          W4   = (float*)((char*)d_ws + off_W4);
    float*          bvec = (float*)((char*)d_ws + off_bv);
    float*          PQ   = (float*)((char*)d_ws + off_PQ);
    unsigned*       bcnt = (unsigned*)((char*)d_ws + off_bc);

    prep<<<200, 256, 0, stream>>>(emb, bn, Wf, bfv, Wb, bb, Aemb, WT, W4, bvec, bcnt);
    gemmG<<<72, 256, 0, stream>>>(X, Aemb, WT, bvec, G1, Gb);
    scanF<<<512, 512, 0, stream>>>(X, G1, Gb, W4, Wn, Wo, bo, PQ, bcnt, out);
}